// Round 2
// baseline (14976.875 us; speedup 1.0000x reference)
//
#include <hip/hip_runtime.h>
#include <hip/hip_bf16.h>

typedef short  short8  __attribute__((ext_vector_type(8)));
typedef float  float4v __attribute__((ext_vector_type(4)));

#define NSTEPS 60

// Tsit5 coefficients premultiplied by H = 1/60
constexpr double Hd = 1.0 / 60.0;
constexpr float HA1[1] = { (float)(Hd * 0.161) };
constexpr float HA2[2] = { (float)(Hd * -0.008480655492356989), (float)(Hd * 0.335480655492357) };
constexpr float HA3[3] = { (float)(Hd * 2.8971530571054935), (float)(Hd * -6.359448489975075),
                           (float)(Hd * 4.3622954328695815) };
constexpr float HA4[4] = { (float)(Hd * 5.325864828439257), (float)(Hd * -11.748883564062828),
                           (float)(Hd * 7.4955393428898365), (float)(Hd * -0.09249506636175525) };
constexpr float HA5[5] = { (float)(Hd * 5.86145544294642), (float)(Hd * -12.92096931784711),
                           (float)(Hd * 8.159367898576159), (float)(Hd * -0.071584973281401),
                           (float)(Hd * -0.028269050394068383) };
constexpr float HB6[6] = { (float)(Hd * 0.09646076681806523), (float)(Hd * 0.01),
                           (float)(Hd * 0.4798896504144996), (float)(Hd * 1.379008574103742),
                           (float)(Hd * -3.290069515436081), (float)(Hd * 2.324710524099774) };

__device__ __forceinline__ unsigned short f2bf(float f) {
    union { float f; unsigned u; } v; v.f = f;
    unsigned r = v.u + 0x7fffu + ((v.u >> 16) & 1u);   // RNE
    return (unsigned short)(r >> 16);
}

// Weight conversion: f32 row-major -> bf16 in MFMA-fragment-linear block layout.
// Block (ntile, kstep) of a layer = 1024 B; lane l holds W[n = ntile*16 + (l&15)]
// [k = kstep*32 + (l>>4)*8 .. +8]  (the exact B-fragment of mfma_f32_16x16x32_bf16).
// ws layout (shorts): [W1y: 256 blks][W2: 512 blks][W3: 256 blks], 1 MB total.
__global__ void wconv(const float* __restrict__ W1, const float* __restrict__ W2,
                      const float* __restrict__ W3, unsigned short* __restrict__ ws) {
    int g = blockIdx.x * blockDim.x + threadIdx.x;   // chunk id, 0..65535
    int blk = g >> 6, l = g & 63;
    const float* src;
    if (blk < 256) {                 // W1y: N=512, K=256 (first 256 input cols of W1)
        int b = blk; int nt = b >> 3, ks = b & 7;
        int n = nt * 16 + (l & 15), k = ks * 32 + (l >> 4) * 8;
        src = W1 + n * 512 + k;
    } else if (blk < 768) {          // W2: N=512, K=512
        int b = blk - 256; int nt = b >> 4, ks = b & 15;
        int n = nt * 16 + (l & 15), k = ks * 32 + (l >> 4) * 8;
        src = W2 + n * 512 + k;
    } else {                         // W3: N=256, K=512
        int b = blk - 768; int nt = b >> 4, ks = b & 15;
        int n = nt * 16 + (l & 15), k = ks * 32 + (l >> 4) * 8;
        src = W3 + n * 512 + k;
    }
    short8 v;
#pragma unroll
    for (int j = 0; j < 8; ++j) v[j] = (short)f2bf(src[j]);
    *(((short8*)ws) + g) = v;
}

// A-fragments from XOR-swizzled LDS, B-fragments streamed from global (block layout).
template<int KDIM, int NT>
__device__ __forceinline__ void mfma_block(const unsigned short* __restrict__ lds, int stride,
                                           const short8* __restrict__ wb, int ntg0, int lane,
                                           float4v* acc) {
    const int row  = lane & 15;
    const int koff = (lane >> 4) * 8;
    const int rm   = (row & 7) << 3;      // XOR swizzle in 8-short units
#pragma unroll
    for (int ks = 0; ks < KDIM / 32; ++ks) {
        const int nidx = ks * 32 + koff;
        short8 a = *(const short8*)(lds + row * stride + (nidx ^ rm));
#pragma unroll
        for (int nt = 0; nt < NT; ++nt) {
            short8 b = wb[(size_t)((ntg0 + nt) * (KDIM / 32) + ks) * 64 + lane];
            acc[nt] = __builtin_amdgcn_mfma_f32_16x16x32_bf16(a, b, acc[nt], 0, 0, 0);
        }
    }
}

// One WG = 8 trajectory rows, 8 waves, entire 60-step integration. No inter-WG comm.
__global__ void __launch_bounds__(512, 2) odeint(
        const float* __restrict__ x0, const float* __restrict__ uf,
        const float* __restrict__ W1, const float* __restrict__ b1,
        const float* __restrict__ b2, const float* __restrict__ b3,
        const unsigned short* __restrict__ ws, float* __restrict__ out) {
    __shared__ unsigned short xb[16 * 256];   // stage input, bf16, XOR-swizzled (rows 8-15 dummy)
    __shared__ unsigned short hb[16 * 512];   // hidden acts, bf16, XOR-swizzled (reused h1/h2)
    __shared__ float c1s[8 * 512];            // W1u@u + b1 per row
    __shared__ float bias2[512];
    __shared__ float bias3[256];

    const int tid  = threadIdx.x;
    const int wave = tid >> 6, lane = tid & 63;
    const int r0   = blockIdx.x * 8;

    // ---- stage u into hb (as f32 scratch) ----
    float* utmp = (float*)hb;                 // 8 KB of the 16 KB buffer
    for (int i = tid; i < 8 * 256; i += 512) {
        int row = i >> 8, k = i & 255;
        int g = r0 + row;
        utmp[i] = (g < 1024) ? uf[g * 256 + k] : 0.f;   // branch 1: zero force
    }
    bias2[tid] = b2[tid];
    if (tid < 256) bias3[tid] = b3[tid];
    __syncthreads();

    // ---- c1 = W1u @ u + b1 (one-time, f32 VALU) ----
    {
        int n = tid;                           // each thread owns neuron n for all 8 rows
        float acc8[8];
#pragma unroll
        for (int r = 0; r < 8; ++r) acc8[r] = b1[n];
        const float* wrow = W1 + n * 512 + 256;
        for (int k = 0; k < 256; ++k) {
            float w = wrow[k];
#pragma unroll
            for (int r = 0; r < 8; ++r) acc8[r] += w * utmp[r * 256 + k];
        }
#pragma unroll
        for (int r = 0; r < 8; ++r) c1s[r * 512 + n] = acc8[r];
    }
    __syncthreads();                           // utmp dead; hb free for bf16 use

    // ---- y and k1..k6 live in registers of owner lanes (lane<32, C/D frag layout) ----
    float ybr[8];
    float kreg[6][8];
    if (lane < 32) {
#pragma unroll
        for (int e = 0; e < 8; ++e) {
            int nt = e >> 2, r = e & 3;
            int row = (lane >> 4) * 4 + r;
            int n   = (wave * 2 + nt) * 16 + (lane & 15);
            int g   = r0 + row;
            ybr[e] = x0[(g & 1023) * 256 + n];
        }
    }

    const short8* wy1 = (const short8*)ws;
    const short8* w2  = (const short8*)(ws + 131072);   // +256 KB
    const short8* w3  = (const short8*)(ws + 393216);   // +768 KB

#define DO_STAGE(S, COEF) do {                                                          \
    if (lane < 32) {                                                                    \
        _Pragma("unroll")                                                               \
        for (int e = 0; e < 8; ++e) {                                                   \
            int nt_ = e >> 2, r_ = e & 3;                                               \
            int row_ = (lane >> 4) * 4 + r_;                                            \
            int n_   = (wave * 2 + nt_) * 16 + (lane & 15);                             \
            float v_ = ybr[e];                                                          \
            _Pragma("unroll")                                                           \
            for (int j = 0; j < S; ++j) v_ += COEF[j] * kreg[j][e];                     \
            xb[row_ * 256 + (n_ ^ ((row_ & 7) << 3))] = f2bf(v_);                       \
        }                                                                               \
    }                                                                                   \
    __syncthreads();  /* A: xb ready; also all prev-stage hb reads drained */           \
    {   /* layer 1: K=256 from xb, +c1, relu -> hb */                                   \
        float4v a1[4];                                                                  \
        _Pragma("unroll") for (int q = 0; q < 4; ++q) a1[q] = (float4v){0.f,0.f,0.f,0.f}; \
        mfma_block<256, 4>(xb, 256, wy1, wave * 4, lane, a1);                           \
        if (lane < 32) {                                                                \
            _Pragma("unroll")                                                           \
            for (int nt = 0; nt < 4; ++nt) {                                            \
                int n_g = (wave * 4 + nt) * 16 + (lane & 15);                           \
                _Pragma("unroll")                                                       \
                for (int r = 0; r < 4; ++r) {                                           \
                    int row = (lane >> 4) * 4 + r;                                      \
                    float v = a1[nt][r] + c1s[row * 512 + n_g];                         \
                    v = fmaxf(v, 0.f);                                                  \
                    hb[row * 512 + (n_g ^ ((row & 7) << 3))] = f2bf(v);                 \
                }                                                                       \
            }                                                                           \
        }                                                                               \
    }                                                                                   \
    __syncthreads();  /* B: h1 ready */                                                 \
    {   /* layer 2: K=512 from hb, +b2, relu -> hb (in-place, barrier-guarded) */       \
        float4v a2[4];                                                                  \
        _Pragma("unroll") for (int q = 0; q < 4; ++q) a2[q] = (float4v){0.f,0.f,0.f,0.f}; \
        mfma_block<512, 4>(hb, 512, w2, wave * 4, lane, a2);                            \
        __syncthreads();  /* C: all reads of h1 done */                                 \
        if (lane < 32) {                                                                \
            _Pragma("unroll")                                                           \
            for (int nt = 0; nt < 4; ++nt) {                                            \
                int n_g = (wave * 4 + nt) * 16 + (lane & 15);                           \
                _Pragma("unroll")                                                       \
                for (int r = 0; r < 4; ++r) {                                           \
                    int row = (lane >> 4) * 4 + r;                                      \
                    float v = a2[nt][r] + bias2[n_g];                                   \
                    v = fmaxf(v, 0.f);                                                  \
                    hb[row * 512 + (n_g ^ ((row & 7) << 3))] = f2bf(v);                 \
                }                                                                       \
            }                                                                           \
        }                                                                               \
    }                                                                                   \
    __syncthreads();  /* D: h2 ready */                                                 \
    {   /* layer 3: K=512 from hb, +b3 -> kreg[S] (registers, no LDS round-trip) */     \
        float4v a3[2];                                                                  \
        _Pragma("unroll") for (int q = 0; q < 2; ++q) a3[q] = (float4v){0.f,0.f,0.f,0.f}; \
        mfma_block<512, 2>(hb, 512, w3, wave * 2, lane, a3);                            \
        if (lane < 32) {                                                                \
            _Pragma("unroll")                                                           \
            for (int nt = 0; nt < 2; ++nt) {                                            \
                int n_g = (wave * 2 + nt) * 16 + (lane & 15);                           \
                _Pragma("unroll")                                                       \
                for (int r = 0; r < 4; ++r) {                                           \
                    kreg[S][nt * 4 + r] = a3[nt][r] + bias3[n_g];                       \
                }                                                                       \
            }                                                                           \
        }                                                                               \
    }                                                                                   \
} while (0)

    for (int step = 0; step < NSTEPS; ++step) {
        DO_STAGE(0, HA1);
        DO_STAGE(1, HA1);
        DO_STAGE(2, HA2);
        DO_STAGE(3, HA3);
        DO_STAGE(4, HA4);
        DO_STAGE(5, HA5);
        if (lane < 32) {               // y update (pure registers, no barrier needed)
#pragma unroll
            for (int e = 0; e < 8; ++e) {
                float v = ybr[e];
#pragma unroll
                for (int j = 0; j < 6; ++j) v += HB6[j] * kreg[j][e];
                ybr[e] = v;
            }
        }
    }
#undef DO_STAGE

    if (lane < 32) {
#pragma unroll
        for (int e = 0; e < 8; ++e) {
            int nt = e >> 2, r = e & 3;
            int row = (lane >> 4) * 4 + r;
            int n   = (wave * 2 + nt) * 16 + (lane & 15);
            out[(r0 + row) * 256 + n] = ybr[e];
        }
    }
}

extern "C" void kernel_launch(void* const* d_in, const int* in_sizes, int n_in,
                              void* d_out, int out_size, void* d_ws, size_t ws_size,
                              hipStream_t stream) {
    const float* x0 = (const float*)d_in[0];
    const float* uf = (const float*)d_in[1];
    const float* W1 = (const float*)d_in[2];
    const float* b1 = (const float*)d_in[3];
    const float* W2 = (const float*)d_in[4];
    const float* b2 = (const float*)d_in[5];
    const float* W3 = (const float*)d_in[6];
    const float* b3 = (const float*)d_in[7];
    unsigned short* ws = (unsigned short*)d_ws;   // 1 MB bf16 weights, rebuilt every call

    wconv<<<128, 512, 0, stream>>>(W1, W2, W3, ws);
    odeint<<<256, 512, 0, stream>>>(x0, uf, W1, b1, b2, b3, ws, (float*)d_out);
}

// Round 3
// 12022.649 us; speedup vs baseline: 1.2457x; 1.2457x over previous
//
#include <hip/hip_runtime.h>
#include <hip/hip_bf16.h>

typedef short  short8  __attribute__((ext_vector_type(8)));
typedef float  float4v __attribute__((ext_vector_type(4)));

#define NSTEPS 60
#define ROWS   16            // trajectory rows per WG (fills MFMA M=16)
#define GRID   128           // 2048 / ROWS
#define C1S    518           // padded f32 stride for c1s (bank-conflict-free)

// Tsit5 coefficients premultiplied by H = 1/60
constexpr double Hd = 1.0 / 60.0;
constexpr float HA1[1] = { (float)(Hd * 0.161) };
constexpr float HA2[2] = { (float)(Hd * -0.008480655492356989), (float)(Hd * 0.335480655492357) };
constexpr float HA3[3] = { (float)(Hd * 2.8971530571054935), (float)(Hd * -6.359448489975075),
                           (float)(Hd * 4.3622954328695815) };
constexpr float HA4[4] = { (float)(Hd * 5.325864828439257), (float)(Hd * -11.748883564062828),
                           (float)(Hd * 7.4955393428898365), (float)(Hd * -0.09249506636175525) };
constexpr float HA5[5] = { (float)(Hd * 5.86145544294642), (float)(Hd * -12.92096931784711),
                           (float)(Hd * 8.159367898576159), (float)(Hd * -0.071584973281401),
                           (float)(Hd * -0.028269050394068383) };
constexpr float HB6[6] = { (float)(Hd * 0.09646076681806523), (float)(Hd * 0.01),
                           (float)(Hd * 0.4798896504144996), (float)(Hd * 1.379008574103742),
                           (float)(Hd * -3.290069515436081), (float)(Hd * 2.324710524099774) };

__device__ __forceinline__ unsigned short f2bf(float f) {
    union { float f; unsigned u; } v; v.f = f;
    unsigned r = v.u + 0x7fffu + ((v.u >> 16) & 1u);   // RNE
    return (unsigned short)(r >> 16);
}

// Weight conversion: f32 row-major -> bf16 in MFMA-fragment-linear block layout.
// Block (ntile, kstep) = 1024 B; lane l holds W[n = ntile*16 + (l&15)]
// [k = kstep*32 + (l>>4)*8 .. +8]  (exact B-fragment of mfma_f32_16x16x32_bf16).
// ws layout (shorts): [W1y: 256 blks][W2: 512 blks][W3: 256 blks], 1 MB total.
__global__ void wconv(const float* __restrict__ W1, const float* __restrict__ W2,
                      const float* __restrict__ W3, unsigned short* __restrict__ ws) {
    int g = blockIdx.x * blockDim.x + threadIdx.x;   // chunk id, 0..65535
    int blk = g >> 6, l = g & 63;
    const float* src;
    if (blk < 256) {                 // W1y: N=512, K=256 (first 256 input cols of W1)
        int b = blk; int nt = b >> 3, ks = b & 7;
        int n = nt * 16 + (l & 15), k = ks * 32 + (l >> 4) * 8;
        src = W1 + n * 512 + k;
    } else if (blk < 768) {          // W2: N=512, K=512
        int b = blk - 256; int nt = b >> 4, ks = b & 15;
        int n = nt * 16 + (l & 15), k = ks * 32 + (l >> 4) * 8;
        src = W2 + n * 512 + k;
    } else {                         // W3: N=256, K=512
        int b = blk - 768; int nt = b >> 4, ks = b & 15;
        int n = nt * 16 + (l & 15), k = ks * 32 + (l >> 4) * 8;
        src = W3 + n * 512 + k;
    }
    short8 v;
#pragma unroll
    for (int j = 0; j < 8; ++j) v[j] = (short)f2bf(src[j]);
    *(((short8*)ws) + g) = v;
}

// A-fragments from XOR-swizzled LDS; B-fragments streamed from global, 1-deep
// software pipeline (issue ks+1 loads before MFMAing ks).
template<int KDIM, int NT>
__device__ __forceinline__ void mfma_block(const unsigned short* __restrict__ lds, int stride,
                                           const short8* __restrict__ wb, int ntg0, int lane,
                                           float4v* acc) {
    constexpr int KS = KDIM / 32;
    const int row  = lane & 15;
    const int koff = (lane >> 4) * 8;
    const int rm   = (row & 7) << 3;          // XOR swizzle in 8-short units
    const short8* wp = wb + (size_t)ntg0 * KS * 64 + lane;
    short8 a_cur = *(const short8*)(lds + row * stride + (koff ^ rm));
    short8 b_cur[NT];
#pragma unroll
    for (int nt = 0; nt < NT; ++nt) b_cur[nt] = wp[(size_t)nt * KS * 64];
#pragma unroll
    for (int ks = 0; ks < KS; ++ks) {
        short8 a_nxt;
        short8 b_nxt[NT];
        if (ks + 1 < KS) {
            a_nxt = *(const short8*)(lds + row * stride + (((ks + 1) * 32 + koff) ^ rm));
#pragma unroll
            for (int nt = 0; nt < NT; ++nt) b_nxt[nt] = wp[((size_t)nt * KS + ks + 1) * 64];
        }
#pragma unroll
        for (int nt = 0; nt < NT; ++nt)
            acc[nt] = __builtin_amdgcn_mfma_f32_16x16x32_bf16(a_cur, b_cur[nt], acc[nt], 0, 0, 0);
        a_cur = a_nxt;
#pragma unroll
        for (int nt = 0; nt < NT; ++nt) b_cur[nt] = b_nxt[nt];
    }
}

// One WG = 16 trajectory rows, 8 waves, entire 60-step integration. No inter-WG comm.
__global__ void __launch_bounds__(512, 1) odeint(
        const float* __restrict__ x0, const float* __restrict__ uf,
        const float* __restrict__ W1, const float* __restrict__ b1,
        const float* __restrict__ b2, const float* __restrict__ b3,
        const unsigned short* __restrict__ ws, float* __restrict__ out) {
    __shared__ unsigned short xb[16 * 256];   // stage input, bf16, XOR-swizzled (8 KB)
    __shared__ unsigned short h1[16 * 512];   // hidden 1 (16 KB)
    __shared__ unsigned short h2[16 * 512];   // hidden 2 (16 KB) -- separate: drops a barrier
    __shared__ float c1s[16 * C1S];           // W1u@u + b1 per row (padded stride)
    __shared__ float bias2[512];
    __shared__ float bias3[256];

    const int tid  = threadIdx.x;
    const int wave = tid >> 6, lane = tid & 63;
    const int r0   = blockIdx.x * ROWS;

    // ---- stage u (f32) into h1-as-scratch ----
    float* utmp = (float*)h1;                 // 16*256 f32 = 16 KB = sizeof(h1)
    {
        const bool forced = (r0 < 1024);      // rows stacked [forced;unforced]
        float4v* ud = (float4v*)utmp;
        for (int i = tid; i < ROWS * 64; i += 512) {
            int row = i >> 6, c4 = i & 63;
            float4v v = {0.f, 0.f, 0.f, 0.f};
            if (forced) v = *(const float4v*)(uf + (size_t)(r0 + row) * 256 + c4 * 4);
            ud[i] = v;
        }
    }
    bias2[tid] = b2[tid];
    if (tid < 256) bias3[tid] = b3[tid];
    __syncthreads();

    // ---- c1 = W1u @ u + b1 (one-time, f32 VALU; utmp reads broadcast across lanes) ----
    {
        int n = tid;                           // thread owns neuron n for all 16 rows
        float acc16[ROWS];
        float bb = b1[n];
#pragma unroll
        for (int r = 0; r < ROWS; ++r) acc16[r] = bb;
        const float* wrow = W1 + n * 512 + 256;
        for (int k = 0; k < 256; ++k) {
            float w = wrow[k];
#pragma unroll
            for (int r = 0; r < ROWS; ++r) acc16[r] += w * utmp[r * 256 + k];
        }
#pragma unroll
        for (int r = 0; r < ROWS; ++r) c1s[r * C1S + n] = acc16[r];
    }
    __syncthreads();                           // utmp dead; h1 free for bf16 use

    // ---- y and k1..k6 in registers, C/D fragment layout, ALL 64 lanes ----
    // element e = nt*4 + r: row = (lane>>4)*4 + r, col n = (wave*2+nt)*16 + (lane&15)
    float ybr[8];
    float kreg[6][8];
#pragma unroll
    for (int e = 0; e < 8; ++e) {
        int nt = e >> 2, r = e & 3;
        int row = (lane >> 4) * 4 + r;
        int n   = (wave * 2 + nt) * 16 + (lane & 15);
        ybr[e] = x0[(size_t)((r0 + row) & 1023) * 256 + n];
    }

    const short8* wy1 = (const short8*)ws;
    const short8* w2  = (const short8*)(ws + 131072);   // +256 KB
    const short8* w3  = (const short8*)(ws + 393216);   // +768 KB

#define DO_STAGE(S, COEF) do {                                                          \
    {   /* write stage input x = y + sum COEF[j]*k_j  (own columns only) */             \
        _Pragma("unroll")                                                               \
        for (int e = 0; e < 8; ++e) {                                                   \
            int nt_ = e >> 2, r_ = e & 3;                                               \
            int row_ = (lane >> 4) * 4 + r_;                                            \
            int n_   = (wave * 2 + nt_) * 16 + (lane & 15);                             \
            float v_ = ybr[e];                                                          \
            _Pragma("unroll")                                                           \
            for (int j = 0; j < S; ++j) v_ += COEF[j] * kreg[j][e];                     \
            xb[row_ * 256 + (n_ ^ ((row_ & 7) << 3))] = f2bf(v_);                       \
        }                                                                               \
    }                                                                                   \
    __syncthreads();  /* A: xb ready */                                                 \
    {   /* layer 1: K=256 from xb, +c1, relu -> h1 */                                   \
        float4v a1[4];                                                                  \
        _Pragma("unroll") for (int q = 0; q < 4; ++q) a1[q] = (float4v){0.f,0.f,0.f,0.f}; \
        mfma_block<256, 4>(xb, 256, wy1, wave * 4, lane, a1);                           \
        _Pragma("unroll")                                                               \
        for (int nt = 0; nt < 4; ++nt) {                                                \
            int n_g = (wave * 4 + nt) * 16 + (lane & 15);                               \
            _Pragma("unroll")                                                           \
            for (int r = 0; r < 4; ++r) {                                               \
                int row = (lane >> 4) * 4 + r;                                          \
                float v = a1[nt][r] + c1s[row * C1S + n_g];                             \
                v = fmaxf(v, 0.f);                                                      \
                h1[row * 512 + (n_g ^ ((row & 7) << 3))] = f2bf(v);                     \
            }                                                                           \
        }                                                                               \
    }                                                                                   \
    __syncthreads();  /* B: h1 ready */                                                 \
    {   /* layer 2: K=512 from h1, +b2, relu -> h2 (separate buffer, no mid-barrier) */ \
        float4v a2[4];                                                                  \
        _Pragma("unroll") for (int q = 0; q < 4; ++q) a2[q] = (float4v){0.f,0.f,0.f,0.f}; \
        mfma_block<512, 4>(h1, 512, w2, wave * 4, lane, a2);                            \
        _Pragma("unroll")                                                               \
        for (int nt = 0; nt < 4; ++nt) {                                                \
            int n_g = (wave * 4 + nt) * 16 + (lane & 15);                               \
            _Pragma("unroll")                                                           \
            for (int r = 0; r < 4; ++r) {                                               \
                int row = (lane >> 4) * 4 + r;                                          \
                float v = a2[nt][r] + bias2[n_g];                                       \
                v = fmaxf(v, 0.f);                                                      \
                h2[row * 512 + (n_g ^ ((row & 7) << 3))] = f2bf(v);                     \
            }                                                                           \
        }                                                                               \
    }                                                                                   \
    __syncthreads();  /* D: h2 ready (also orders next-stage h1 writes after h1 reads) */ \
    {   /* layer 3: K=512 from h2, +b3 -> kreg[S] (registers, no LDS round-trip) */     \
        float4v a3[2];                                                                  \
        _Pragma("unroll") for (int q = 0; q < 2; ++q) a3[q] = (float4v){0.f,0.f,0.f,0.f}; \
        mfma_block<512, 2>(h2, 512, w3, wave * 2, lane, a3);                            \
        _Pragma("unroll")                                                               \
        for (int nt = 0; nt < 2; ++nt) {                                                \
            int n_g = (wave * 2 + nt) * 16 + (lane & 15);                               \
            _Pragma("unroll")                                                           \
            for (int r = 0; r < 4; ++r) {                                               \
                kreg[S][nt * 4 + r] = a3[nt][r] + bias3[n_g];                           \
            }                                                                           \
        }                                                                               \
    }                                                                                   \
} while (0)

    for (int step = 0; step < NSTEPS; ++step) {
        DO_STAGE(0, HA1);
        DO_STAGE(1, HA1);
        DO_STAGE(2, HA2);
        DO_STAGE(3, HA3);
        DO_STAGE(4, HA4);
        DO_STAGE(5, HA5);
        {   // y update (pure registers, no barrier needed)
#pragma unroll
            for (int e = 0; e < 8; ++e) {
                float v = ybr[e];
#pragma unroll
                for (int j = 0; j < 6; ++j) v += HB6[j] * kreg[j][e];
                ybr[e] = v;
            }
        }
    }
#undef DO_STAGE

#pragma unroll
    for (int e = 0; e < 8; ++e) {
        int nt = e >> 2, r = e & 3;
        int row = (lane >> 4) * 4 + r;
        int n   = (wave * 2 + nt) * 16 + (lane & 15);
        out[(size_t)(r0 + row) * 256 + n] = ybr[e];
    }
}

extern "C" void kernel_launch(void* const* d_in, const int* in_sizes, int n_in,
                              void* d_out, int out_size, void* d_ws, size_t ws_size,
                              hipStream_t stream) {
    const float* x0 = (const float*)d_in[0];
    const float* uf = (const float*)d_in[1];
    const float* W1 = (const float*)d_in[2];
    const float* b1 = (const float*)d_in[3];
    const float* W2 = (const float*)d_in[4];
    const float* b2 = (const float*)d_in[5];
    const float* W3 = (const float*)d_in[6];
    const float* b3 = (const float*)d_in[7];
    unsigned short* ws = (unsigned short*)d_ws;   // 1 MB bf16 weights, rebuilt every call

    wconv<<<128, 512, 0, stream>>>(W1, W2, W3, ws);
    odeint<<<GRID, 512, 0, stream>>>(x0, uf, W1, b1, b2, b3, ws, (float*)d_out);
}